// Round 5
// baseline (714.318 us; speedup 1.0000x reference)
//
#include <hip/hip_runtime.h>
#include <math.h>

#define B_    256
#define NCH   32
#define T_    2000
#define NTF   4
#define NSF   40
#define NSUB  20
#define TK    25
#define NCLS  4
#define NTAN  210
#define NPAIR 820
#define ACC_STRIDE 860
#define TILE_T 250
#define NTILE  8
#define PL     12

#define ACC_FLOATS (B_*ACC_STRIDE)
#define W2T_OFF ACC_FLOATS                    // 5120 floats, [s][c][f]
#define W1T_OFF (ACC_FLOATS + NSF*NTF*NCH)    // 100 floats,  [k][f]

#define XS_TSTR 36
#define H2_STR  260
#define LDS_DW  10400

typedef float v2f __attribute__((ext_vector_type(2)));

__device__ __forceinline__ v2f fma2(v2f a, v2f b, v2f c) {
#if __has_builtin(__builtin_elementwise_fma)
    return __builtin_elementwise_fma(a, b, c);
#else
    v2f r; r.x = fmaf(a.x, b.x, c.x); r.y = fmaf(a.y, b.y, c.y); return r;
#endif
}

__device__ __forceinline__ int pack_ut(int f, int g) {
    return f*NSF - (f*(f-1))/2 + (g - f);
}

// ---------------- K0: weight transpose ----------------
__global__ void prep_kernel(const float* __restrict__ conv1_w,
                            const float* __restrict__ conv2_w,
                            float* __restrict__ ws) {
    int tid = threadIdx.x;
    float* w2t = ws + W2T_OFF;
    float* w1t = ws + W1T_OFF;
    for (int i = tid; i < NSF*NTF*NCH; i += 256) {
        int f  = i & 3;
        int sc = i >> 2;
        int c  = sc & 31;
        int s  = sc >> 5;
        w2t[i] = conv2_w[(s*NTF + f)*NCH + c];
    }
    for (int i = tid; i < NTF*TK; i += 256) {
        int f = i & 3;
        int k = i >> 2;
        w1t[i] = conv1_w[f*TK + k];
    }
}

// ---------------- K1: fused conv1+conv2+gram (R4 structure, verified on first call) ----------------
__global__ __launch_bounds__(256, 2)
void conv_gram_kernel(const float* __restrict__ x,
                      const float* __restrict__ conv1_b,
                      const float* __restrict__ conv2_b,
                      const float* __restrict__ wts,
                      float* __restrict__ acc)
{
    __shared__ float lds[LDS_DW];   // union: xs[280][36] then h2[40][260]

    const int tid  = threadIdx.x;
    const int bid  = blockIdx.x;
    const int b    = bid >> 3;
    const int tile = bid & 7;
    const int t0   = tile * TILE_T;

    const float* xb = x + (size_t)b*NCH*T_;
    for (int li = tid; li < NCH*280; li += 256) {
        int c = li / 280;
        int i = li - c*280;
        int tg = t0 + i - PL;
        tg = (tg < 0) ? -tg : tg;
        tg = (tg >= T_) ? (2*T_ - 2 - tg) : tg;
        lds[i*XS_TSTR + c] = xb[c*T_ + tg];
    }
    __syncthreads();

    const float4* w1t = (const float4*)(wts + W1T_OFF);
    const float4* w2t = (const float4*)(wts + W2T_OFF);

    float h2acc[NSF];
    #pragma unroll
    for (int s = 0; s < NSF; ++s) h2acc[s] = conv2_b[s];

    const float b1_0 = conv1_b[0], b1_1 = conv1_b[1], b1_2 = conv1_b[2], b1_3 = conv1_b[3];

    for (int g = 0; g < 4; ++g) {
        v2f h1g[16];
        #pragma unroll
        for (int c = 0; c < 8; ++c) {
            v2f lo; lo.x = b1_0; lo.y = b1_1;
            v2f hi; hi.x = b1_2; hi.y = b1_3;
            h1g[2*c]   = lo;
            h1g[2*c+1] = hi;
        }
        #pragma clang loop unroll(disable)
        for (int k = 0; k < TK; ++k) {
            float4 wq = w1t[k];
            v2f w01; w01.x = wq.x; w01.y = wq.y;
            v2f w23; w23.x = wq.z; w23.y = wq.w;
            const float4* xp = (const float4*)&lds[(tid + k)*XS_TSTR + 8*g];
            float4 xa = xp[0];
            float4 xc = xp[1];
            float xv0 = xa.x, xv1 = xa.y, xv2 = xa.z, xv3 = xa.w;
            float xv4 = xc.x, xv5 = xc.y, xv6 = xc.z, xv7 = xc.w;
            v2f t;
            t.x = xv0; t.y = xv0; h1g[0]  = fma2(t, w01, h1g[0]);  h1g[1]  = fma2(t, w23, h1g[1]);
            t.x = xv1; t.y = xv1; h1g[2]  = fma2(t, w01, h1g[2]);  h1g[3]  = fma2(t, w23, h1g[3]);
            t.x = xv2; t.y = xv2; h1g[4]  = fma2(t, w01, h1g[4]);  h1g[5]  = fma2(t, w23, h1g[5]);
            t.x = xv3; t.y = xv3; h1g[6]  = fma2(t, w01, h1g[6]);  h1g[7]  = fma2(t, w23, h1g[7]);
            t.x = xv4; t.y = xv4; h1g[8]  = fma2(t, w01, h1g[8]);  h1g[9]  = fma2(t, w23, h1g[9]);
            t.x = xv5; t.y = xv5; h1g[10] = fma2(t, w01, h1g[10]); h1g[11] = fma2(t, w23, h1g[11]);
            t.x = xv6; t.y = xv6; h1g[12] = fma2(t, w01, h1g[12]); h1g[13] = fma2(t, w23, h1g[13]);
            t.x = xv7; t.y = xv7; h1g[14] = fma2(t, w01, h1g[14]); h1g[15] = fma2(t, w23, h1g[15]);
        }
        #pragma unroll
        for (int s = 0; s < NSF; ++s) {
            v2f a2; a2.x = 0.f; a2.y = 0.f;
            #pragma unroll
            for (int c = 0; c < 8; ++c) {
                float4 wq = w2t[s*NCH + 8*g + c];
                v2f w01; w01.x = wq.x; w01.y = wq.y;
                v2f w23; w23.x = wq.z; w23.y = wq.w;
                a2 = fma2(w01, h1g[2*c],   a2);
                a2 = fma2(w23, h1g[2*c+1], a2);
            }
            h2acc[s] += a2.x + a2.y;
        }
    }
    __syncthreads();

    #pragma unroll
    for (int s = 0; s < NSF; ++s) {
        float vw = (tid < TILE_T) ? h2acc[s] : 0.f;
        lds[s*H2_STR + tid] = vw;
    }
    for (int i = tid; i < NSF*4; i += 256) {
        int s = i >> 2, col = 256 + (i & 3);
        lds[s*H2_STR + col] = 0.f;
    }
    __syncthreads();

    float* accb = acc + b*ACC_STRIDE;

    if (tid < 220) {
        int tilei = tid >> 2, chunk = tid & 3;
        int bf = 0, rem = tilei;
        while (rem >= 10 - bf) { rem -= 10 - bf; bf++; }
        int bg = bf + rem;
        int q0 = chunk * 16;
        int qn = (chunk == 3) ? 17 : 16;

        const float4* rA[4];
        const float4* rB[4];
        #pragma unroll
        for (int a = 0; a < 4; ++a) {
            rA[a] = (const float4*)&lds[(bf + 10*a)*H2_STR] + q0;
            rB[a] = (const float4*)&lds[(bg + 10*a)*H2_STR] + q0;
        }
        v2f accL[16], accH[16];
        #pragma unroll
        for (int i = 0; i < 16; ++i) { accL[i].x = 0.f; accL[i].y = 0.f; accH[i] = accL[i]; }

        for (int q = 0; q < qn; ++q) {
            float4 av[4], bv[4];
            #pragma unroll
            for (int a = 0; a < 4; ++a) av[a] = rA[a][q];
            #pragma unroll
            for (int a = 0; a < 4; ++a) bv[a] = rB[a][q];
            #pragma unroll
            for (int a = 0; a < 4; ++a) {
                v2f aL; aL.x = av[a].x; aL.y = av[a].y;
                v2f aH; aH.x = av[a].z; aH.y = av[a].w;
                #pragma unroll
                for (int gI = 0; gI < 4; ++gI) {
                    v2f bL; bL.x = bv[gI].x; bL.y = bv[gI].y;
                    v2f bH; bH.x = bv[gI].z; bH.y = bv[gI].w;
                    accL[a*4+gI] = fma2(aL, bL, accL[a*4+gI]);
                    accH[a*4+gI] = fma2(aH, bH, accH[a*4+gI]);
                }
            }
        }
        #pragma unroll
        for (int a = 0; a < 4; ++a) {
            #pragma unroll
            for (int gI = 0; gI < 4; ++gI) {
                int f  = bf + 10*a;
                int gg = bg + 10*gI;
                if (bf != bg || a <= gI) {
                    int lo = f < gg ? f : gg;
                    int hi = f < gg ? gg : f;
                    v2f sL = accL[a*4+gI], sH = accH[a*4+gI];
                    float s = (sL.x + sL.y) + (sH.x + sH.y);
                    atomicAdd(&accb[pack_ut(lo, hi)], s);
                }
            }
        }
    }

    if (tid < 160) {
        int row = tid >> 2, chunk = tid & 3;
        int q0 = chunk * 16;
        int qn = (chunk == 3) ? 17 : 16;
        const float4* rr = (const float4*)&lds[row*H2_STR] + q0;
        float cs = 0.f;
        for (int q = 0; q < qn; ++q) {
            float4 v = rr[q];
            cs += (v.x + v.y) + (v.z + v.w);
        }
        atomicAdd(&accb[NPAIR + row], cs);
    }
}

// ---------------- K2: 1-barrier/round fused Jacobi, redundant rotation compute ----------------
__device__ __forceinline__ void pq_sched(int r, int k, int& p, int& q) {
    if (k == 0) { p = 19; q = r; }
    else {
        int a = r + k;      if (a >= 19) a -= 19;
        int d = r - k + 19; if (d >= 19) d -= 19;
        p = a; q = d;
    }
}

__device__ __forceinline__ void rotcs(float app, float aqq, float apq,
                                      float& c, float& s) {
    if (fabsf(apq) > 1e-30f) {
        float tau = (aqq - app) * __builtin_amdgcn_rcpf(2.f*apq);
        float sq  = __builtin_amdgcn_sqrtf(fmaf(tau, tau, 1.f));
        float t   = __builtin_amdgcn_rcpf(fabsf(tau) + sq);
        t = (tau < 0.f) ? -t : t;
        c = __builtin_amdgcn_rsqf(fmaf(t, t, 1.f));
        s = t * c;
    } else { c = 1.f; s = 0.f; }
}

__global__ __launch_bounds__(64)
void finalize_kernel(const float* __restrict__ acc,
                     const float* __restrict__ W_bimap,
                     const float* __restrict__ clf_w,
                     const float* __restrict__ clf_b,
                     float* __restrict__ out)
{
    __shared__ float C[NSF*NSF];
    __shared__ float Wb[NSUB*NSF];
    __shared__ float M[NSUB*NSF];
    __shared__ float A[NSUB*21];
    __shared__ float V[NSUB*21];
    __shared__ float lam[NSUB];
    __shared__ float z[NTAN];

    const int tid = threadIdx.x;
    const int b   = blockIdx.x;
    const float* accb = acc + b*ACC_STRIDE;

    for (int i = tid; i < NSF*NSF; i += 64) {
        int f = i / NSF, g = i % NSF;
        int lo = f < g ? f : g;
        int hi = f < g ? g : f;
        double G  = (double)accb[pack_ut(lo, hi)];
        double sf = (double)accb[NPAIR + f];
        double sg = (double)accb[NPAIR + g];
        C[i] = (float)((G - sf*sg*(1.0/2000.0)) * (1.0/1999.0));
    }
    for (int i = tid; i < NSUB*NSF; i += 64) Wb[i] = W_bimap[i];
    __syncthreads();

    for (int i = tid; i < NSUB*NSF; i += 64) {
        int r = i / NSF, g = i % NSF;
        float s = 0.f;
        #pragma unroll 8
        for (int f = 0; f < NSF; ++f) s = fmaf(Wb[r*NSF+f], C[f*NSF+g], s);
        M[i] = s;
    }
    __syncthreads();

    for (int i = tid; i < NSUB*NSUB; i += 64) {
        int r = i / NSUB, j = i % NSUB;
        float s = 0.f;
        #pragma unroll 8
        for (int g = 0; g < NSF; ++g) s = fmaf(M[r*NSF+g], Wb[j*NSF+g], s);
        A[r*21+j] = s;
        V[r*21+j] = (r == j) ? 1.f : 0.f;
    }
    __syncthreads();

    // items: i0 = tid (0..63), i1 = tid+64 (valid iff tid<36); item = (k,l) = (i/10, i%10)
    const int k0 = tid / 10, l0 = tid - 10*(tid/10);
    const bool has1 = (tid < 36);
    const int i1 = tid + 64;
    const int k1 = i1 / 10, l1 = i1 - 10*(i1/10);

    for (int sweep = 0; sweep < 7; ++sweep) {
        for (int r = 0; r < 19; ++r) {
            // ---- decode pairs ----
            int pk0, qk0, pl0, ql0, pk1, qk1, pl1, ql1;
            pq_sched(r, k0, pk0, qk0);
            pq_sched(r, l0, pl0, ql0);
            pq_sched(r, k1, pk1, qk1);
            pq_sched(r, l1, pl1, ql1);

            // ---- ALL reads (pre-round A/V), program-order before any write ----
            float kpp0 = A[pk0*21+pk0], kqq0 = A[qk0*21+qk0], kpq0 = A[pk0*21+qk0];
            float lpp0 = A[pl0*21+pl0], lqq0 = A[ql0*21+ql0], lpq0 = A[pl0*21+ql0];
            float a00_0 = A[pk0*21+pl0], a01_0 = A[pk0*21+ql0];
            float a10_0 = A[qk0*21+pl0], a11_0 = A[qk0*21+ql0];
            float v00_0 = V[pk0*21+pl0], v01_0 = V[pk0*21+ql0];
            float v10_0 = V[qk0*21+pl0], v11_0 = V[qk0*21+ql0];

            float kpp1=0.f, kqq1=0.f, kpq1=0.f, lpp1=0.f, lqq1=0.f, lpq1=0.f;
            float a00_1=0.f, a01_1=0.f, a10_1=0.f, a11_1=0.f;
            float v00_1=0.f, v01_1=0.f, v10_1=0.f, v11_1=0.f;
            if (has1) {
                kpp1 = A[pk1*21+pk1]; kqq1 = A[qk1*21+qk1]; kpq1 = A[pk1*21+qk1];
                lpp1 = A[pl1*21+pl1]; lqq1 = A[ql1*21+ql1]; lpq1 = A[pl1*21+ql1];
                a00_1 = A[pk1*21+pl1]; a01_1 = A[pk1*21+ql1];
                a10_1 = A[qk1*21+pl1]; a11_1 = A[qk1*21+ql1];
                v00_1 = V[pk1*21+pl1]; v01_1 = V[pk1*21+ql1];
                v10_1 = V[qk1*21+pl1]; v11_1 = V[qk1*21+ql1];
            }

            // ---- redundant rotation computation (identical across items) ----
            float ck0, sk0, cl0, sl0, ck1, sk1, cl1, sl1;
            rotcs(kpp0, kqq0, kpq0, ck0, sk0);
            rotcs(lpp0, lqq0, lpq0, cl0, sl0);
            rotcs(kpp1, kqq1, kpq1, ck1, sk1);
            rotcs(lpp1, lqq1, lpq1, cl1, sl1);

            // ---- apply + writes, item0 ----
            {
                float t00 = ck0*a00_0 - sk0*a10_0, t01 = ck0*a01_0 - sk0*a11_0;
                float t10 = sk0*a00_0 + ck0*a10_0, t11 = sk0*a01_0 + ck0*a11_0;
                A[pk0*21+pl0] = cl0*t00 - sl0*t01;
                A[pk0*21+ql0] = sl0*t00 + cl0*t01;
                A[qk0*21+pl0] = cl0*t10 - sl0*t11;
                A[qk0*21+ql0] = sl0*t10 + cl0*t11;
                V[pk0*21+pl0] = cl0*v00_0 - sl0*v01_0;
                V[pk0*21+ql0] = sl0*v00_0 + cl0*v01_0;
                V[qk0*21+pl0] = cl0*v10_0 - sl0*v11_0;
                V[qk0*21+ql0] = sl0*v10_0 + cl0*v11_0;
            }
            if (has1) {
                float t00 = ck1*a00_1 - sk1*a10_1, t01 = ck1*a01_1 - sk1*a11_1;
                float t10 = sk1*a00_1 + ck1*a10_1, t11 = sk1*a01_1 + ck1*a11_1;
                A[pk1*21+pl1] = cl1*t00 - sl1*t01;
                A[pk1*21+ql1] = sl1*t00 + cl1*t01;
                A[qk1*21+pl1] = cl1*t10 - sl1*t11;
                A[qk1*21+ql1] = sl1*t10 + cl1*t11;
                V[pk1*21+pl1] = cl1*v00_1 - sl1*v01_1;
                V[pk1*21+ql1] = sl1*v00_1 + cl1*v01_1;
                V[qk1*21+pl1] = cl1*v10_1 - sl1*v11_1;
                V[qk1*21+ql1] = sl1*v10_1 + cl1*v11_1;
            }
            __syncthreads();   // single-wave barrier: cheap, enforces ordering
        }
    }

    if (tid < NSUB) {
        float w = A[tid*21+tid];
        lam[tid] = logf(fmaxf(w, 1e-4f));
    }
    __syncthreads();

    for (int p = tid; p < NTAN; p += 64) {
        int i = 0, rem = p;
        while (rem >= NSUB - i) { rem -= NSUB - i; i++; }
        int j = i + rem;
        float s = 0.f;
        #pragma unroll 5
        for (int k = 0; k < NSUB; ++k) s = fmaf(V[i*21+k]*lam[k], V[j*21+k], s);
        z[p] = (i == j) ? s : s * 1.41421356237309515f;
    }
    __syncthreads();

    if (tid < NCLS) {
        float s = clf_b[tid];
        for (int p = 0; p < NTAN; ++p) s = fmaf(clf_w[tid*NTAN+p], z[p], s);
        out[b*NCLS + tid] = s;
    }
}

// ---------------- launch ----------------
extern "C" void kernel_launch(void* const* d_in, const int* in_sizes, int n_in,
                              void* d_out, int out_size, void* d_ws, size_t ws_size,
                              hipStream_t stream) {
    const float* x       = (const float*)d_in[0];
    const float* conv1_w = (const float*)d_in[1];
    const float* conv1_b = (const float*)d_in[2];
    const float* conv2_w = (const float*)d_in[3];
    const float* conv2_b = (const float*)d_in[4];
    const float* W_bimap = (const float*)d_in[5];
    const float* clf_w   = (const float*)d_in[6];
    const float* clf_b   = (const float*)d_in[7];
    float* out = (float*)d_out;
    float* ws  = (float*)d_ws;

    hipMemsetAsync(ws, 0, (size_t)ACC_FLOATS*sizeof(float), stream);

    prep_kernel<<<1, 256, 0, stream>>>(conv1_w, conv2_w, ws);
    conv_gram_kernel<<<B_*NTILE, 256, 0, stream>>>(x, conv1_b, conv2_b, ws, ws);
    finalize_kernel<<<B_, 64, 0, stream>>>(ws, W_bimap, clf_w, clf_b, out);
}